// Round 1
// baseline (266.406 us; speedup 1.0000x reference)
//
#include <hip/hip_runtime.h>

// Problem constants (from reference)
constexpr int D_OUT    = 4096;
constexpr int D_IN     = 11008;
constexpr int REMAINED = 5504;
constexpr int NV       = D_IN / 4;   // 2752 float4 per weight row (row bytes 44032, 16B aligned)
constexpr int BLK      = 256;
constexpr int ROWS     = 4;          // rows per block: xd L2 reuse x4, 8 loads in flight/thread

// Scatter x into dense xd: xd[cols[i]] += x[i]. Duplicates exist (randint with
// replacement) -> atomicAdd. xd is pre-zeroed by hipMemsetAsync.
__global__ __launch_bounds__(BLK) void scatter_kernel(
    const float* __restrict__ x,
    const int*   __restrict__ act_idx,
    const int*   __restrict__ cluster,
    float*       __restrict__ xd)
{
    int i = blockIdx.x * BLK + threadIdx.x;
    if (i < REMAINED) {
        int c   = cluster[0];                         // little-endian: works for i32 or low word of i64
        int col = act_idx[(size_t)c * REMAINED + i];
        atomicAdd(xd + col, x[i]);
    }
}

// Dense GEMV: out[j] = dot(W[j,:], xd) + bias[j]. Fully coalesced float4 row
// streaming — this converts the uncoalescable column-gather into a stream of
// the exact same HBM line footprint with 100% line utilization.
__global__ __launch_bounds__(BLK) void gemv_kernel(
    const float4* __restrict__ W,
    const float4* __restrict__ xd,
    const float*  __restrict__ bias,
    float*        __restrict__ out)
{
    const int row0 = blockIdx.x * ROWS;
    const int tid  = threadIdx.x;
    const float4* w0 = W + (size_t)row0 * NV;

    float acc[ROWS] = {0.f, 0.f, 0.f, 0.f};
    for (int k = tid; k < NV; k += BLK) {           // 11 iters (last partial)
        float4 xv = xd[k];
        #pragma unroll
        for (int r = 0; r < ROWS; ++r) {
            float4 w = w0[(size_t)r * NV + k];
            acc[r] += w.x * xv.x + w.y * xv.y + w.z * xv.z + w.w * xv.w;
        }
    }

    // Per-wave shuffle reduce (wave=64), then cross-wave LDS reduce.
    __shared__ float red[ROWS][BLK / 64];
    const int lane = tid & 63;
    const int wave = tid >> 6;
    #pragma unroll
    for (int r = 0; r < ROWS; ++r) {
        float v = acc[r];
        #pragma unroll
        for (int off = 32; off > 0; off >>= 1)
            v += __shfl_down(v, off, 64);
        if (lane == 0) red[r][wave] = v;
    }
    __syncthreads();
    if (tid < ROWS) {
        float s = red[tid][0] + red[tid][1] + red[tid][2] + red[tid][3];
        out[row0 + tid] = s + bias[row0 + tid];
    }
}

extern "C" void kernel_launch(void* const* d_in, const int* in_sizes, int n_in,
                              void* d_out, int out_size, void* d_ws, size_t ws_size,
                              hipStream_t stream)
{
    const float* x       = (const float*)d_in[0];
    const float* weight  = (const float*)d_in[1];
    const float* bias    = (const float*)d_in[2];
    const int*   act_idx = (const int*)d_in[3];
    const int*   cluster = (const int*)d_in[4];
    float*       out     = (float*)d_out;
    float*       xd      = (float*)d_ws;   // D_IN floats = 44032 B of scratch

    // d_ws is re-poisoned to 0xAA before every timed launch -> must zero here.
    hipMemsetAsync(xd, 0, D_IN * sizeof(float), stream);
    scatter_kernel<<<(REMAINED + BLK - 1) / BLK, BLK, 0, stream>>>(x, act_idx, cluster, xd);
    gemv_kernel<<<D_OUT / ROWS, BLK, 0, stream>>>(
        (const float4*)weight, (const float4*)xd, bias, out);
}

// Round 3
// 253.595 us; speedup vs baseline: 1.0505x; 1.0505x over previous
//
#include <hip/hip_runtime.h>

// Problem constants (from reference)
constexpr int D_OUT    = 4096;
constexpr int D_IN     = 11008;
constexpr int REMAINED = 5504;
constexpr int NV       = D_IN / 4;   // 2752 float4 per weight row
constexpr int BLK      = 256;
constexpr int ROWS     = 8;          // rows per block -> 512 blocks, 2/CU (LDS-capped)

// Native clang vector type: __builtin_nontemporal_load rejects HIP_vector_type
// (a struct) but accepts vectors-of-float.
typedef float fvec4 __attribute__((ext_vector_type(4)));

// One fused kernel:
//  1) zero dense xd[D_IN] in LDS
//  2) scatter x through act_idx[cluster] with LDS float atomics (duplicates accumulate)
//  3) stream ROWS weight rows (nontemporal float4, used-once) against LDS xd
//  4) wave-shuffle + LDS reduce, add bias, store
__global__ __launch_bounds__(BLK) void fused_gemv_kernel(
    const float* __restrict__ x,
    const fvec4* __restrict__ W,
    const float* __restrict__ bias,
    const int*   __restrict__ act_idx,
    const int*   __restrict__ cluster,
    float*       __restrict__ out)
{
    __shared__ float xd[D_IN];                 // 44032 B
    __shared__ float red[ROWS][BLK / 64];

    const int tid = threadIdx.x;

    // (1) zero
    #pragma unroll
    for (int i = tid; i < D_IN; i += BLK) xd[i] = 0.f;
    __syncthreads();

    // (2) scatter (coalesced idx/x reads; L2/L3-resident after first touch)
    const int  c   = cluster[0];
    const int* idx = act_idx + (size_t)c * REMAINED;
    for (int i = tid; i < REMAINED; i += BLK)
        atomicAdd(&xd[idx[i]], x[i]);
    __syncthreads();

    // (3) dense GEMV over 8 rows: coalesced, nontemporal (each W line used once)
    const int row0 = blockIdx.x * ROWS;
    const fvec4* w0  = W + (size_t)row0 * NV;
    const fvec4* xd4 = (const fvec4*)xd;

    float acc[ROWS] = {};
    for (int k = tid; k < NV; k += BLK) {      // 11 iters (last partial)
        fvec4 xv = xd4[k];                     // ds_read_b128
        #pragma unroll
        for (int r = 0; r < ROWS; ++r) {
            fvec4 w = __builtin_nontemporal_load(&w0[(size_t)r * NV + k]);
            acc[r] = fmaf(w.x, xv.x, fmaf(w.y, xv.y,
                     fmaf(w.z, xv.z, fmaf(w.w, xv.w, acc[r]))));
        }
    }

    // (4) reduce: wave64 shuffle, then cross-wave via LDS
    const int lane = tid & 63;
    const int wave = tid >> 6;
    #pragma unroll
    for (int r = 0; r < ROWS; ++r) {
        float v = acc[r];
        #pragma unroll
        for (int off = 32; off > 0; off >>= 1)
            v += __shfl_down(v, off, 64);
        if (lane == 0) red[r][wave] = v;
    }
    __syncthreads();
    if (tid < ROWS) {
        float s = red[tid][0] + red[tid][1] + red[tid][2] + red[tid][3];
        out[row0 + tid] = s + bias[row0 + tid];
    }
}

extern "C" void kernel_launch(void* const* d_in, const int* in_sizes, int n_in,
                              void* d_out, int out_size, void* d_ws, size_t ws_size,
                              hipStream_t stream)
{
    const float* x       = (const float*)d_in[0];
    const float* weight  = (const float*)d_in[1];
    const float* bias    = (const float*)d_in[2];
    const int*   act_idx = (const int*)d_in[3];
    const int*   cluster = (const int*)d_in[4];
    float*       out     = (float*)d_out;

    fused_gemv_kernel<<<D_OUT / ROWS, BLK, 0, stream>>>(
        x, (const fvec4*)weight, bias, act_idx, cluster, out);
}

// Round 4
// 249.874 us; speedup vs baseline: 1.0662x; 1.0149x over previous
//
#include <hip/hip_runtime.h>

// Problem constants (from reference)
constexpr int D_OUT    = 4096;
constexpr int D_IN     = 11008;
constexpr int REMAINED = 5504;
constexpr int NV       = D_IN / 4;   // 2752 float4 per weight row
constexpr int BLK      = 256;
constexpr int ROWS     = 8;          // rows per block -> 512 blocks, 2/CU (LDS-capped)

// Native clang vector type: __builtin_nontemporal_load rejects HIP_vector_type.
typedef float fvec4 __attribute__((ext_vector_type(4)));

// Fused scatter+GEMV. Prologue (zero + LDS scatter) is overlapped with the
// first K-iteration's W loads, which are issued before it (no xd dependency).
__global__ __launch_bounds__(BLK) void fused_gemv_kernel(
    const float* __restrict__ x,
    const fvec4* __restrict__ W,
    const float* __restrict__ bias,
    const int*   __restrict__ act_idx,
    const int*   __restrict__ cluster,
    float*       __restrict__ out)
{
    __shared__ float xd[D_IN];                 // 44032 B
    __shared__ float red[ROWS][BLK / 64];

    const int tid  = threadIdx.x;
    const int row0 = blockIdx.x * ROWS;
    const fvec4* w0 = W + (size_t)row0 * NV;

    // (0) prefetch iteration-0 W loads — in flight during the prologue
    fvec4 wpre[ROWS];
    #pragma unroll
    for (int r = 0; r < ROWS; ++r)
        wpre[r] = __builtin_nontemporal_load(&w0[(size_t)r * NV + tid]);

    // (1) zero xd with b128 writes (11 iters vs 43 scalar)
    fvec4* xdw = (fvec4*)xd;
    for (int i = tid; i < NV; i += BLK) xdw[i] = (fvec4)0.f;
    __syncthreads();

    // (2) scatter: vectorized idx/x reads, LDS float atomics (dups accumulate)
    const int c = cluster[0];
    const int4*  idx4 = (const int4*) (act_idx + (size_t)c * REMAINED);
    const fvec4* x4   = (const fvec4*)x;
    for (int i = tid; i < REMAINED / 4; i += BLK) {   // 5.4 iters
        int4  id = idx4[i];
        fvec4 xv = x4[i];
        atomicAdd(&xd[id.x], xv.x);
        atomicAdd(&xd[id.y], xv.y);
        atomicAdd(&xd[id.z], xv.z);
        atomicAdd(&xd[id.w], xv.w);
    }
    __syncthreads();

    // (3) dense GEMV: 8 rows, coalesced nontemporal float4 stream vs LDS xd
    const fvec4* xd4 = (const fvec4*)xd;
    float acc[ROWS] = {};
    {   // iteration 0 from the prefetch
        fvec4 xv = xd4[tid];
        #pragma unroll
        for (int r = 0; r < ROWS; ++r)
            acc[r] = fmaf(wpre[r].x, xv.x, fmaf(wpre[r].y, xv.y,
                     fmaf(wpre[r].z, xv.z, fmaf(wpre[r].w, xv.w, acc[r]))));
    }
    for (int k = tid + BLK; k < NV; k += BLK) {       // 10 more iters (last partial)
        fvec4 xv = xd4[k];
        #pragma unroll
        for (int r = 0; r < ROWS; ++r) {
            fvec4 w = __builtin_nontemporal_load(&w0[(size_t)r * NV + k]);
            acc[r] = fmaf(w.x, xv.x, fmaf(w.y, xv.y,
                     fmaf(w.z, xv.z, fmaf(w.w, xv.w, acc[r]))));
        }
    }

    // (4) reduce: wave64 shuffle, then cross-wave via LDS
    const int lane = tid & 63;
    const int wave = tid >> 6;
    #pragma unroll
    for (int r = 0; r < ROWS; ++r) {
        float v = acc[r];
        #pragma unroll
        for (int off = 32; off > 0; off >>= 1)
            v += __shfl_down(v, off, 64);
        if (lane == 0) red[r][wave] = v;
    }
    __syncthreads();
    if (tid < ROWS) {
        float s = red[tid][0] + red[tid][1] + red[tid][2] + red[tid][3];
        out[row0 + tid] = s + bias[row0 + tid];
    }
}

extern "C" void kernel_launch(void* const* d_in, const int* in_sizes, int n_in,
                              void* d_out, int out_size, void* d_ws, size_t ws_size,
                              hipStream_t stream)
{
    const float* x       = (const float*)d_in[0];
    const float* weight  = (const float*)d_in[1];
    const float* bias    = (const float*)d_in[2];
    const int*   act_idx = (const int*)d_in[3];
    const int*   cluster = (const int*)d_in[4];
    float*       out     = (float*)d_out;

    fused_gemv_kernel<<<D_OUT / ROWS, BLK, 0, stream>>>(
        x, (const fvec4*)weight, bias, act_idx, cluster, out);
}